// Round 13
// baseline (487.939 us; speedup 1.0000x reference)
//
#include <hip/hip_runtime.h>

// ConeIntersection fused kernel for MI355X (gfx950).
// N=4, B=8192, DIM=1024, HEADS=4, HD=256. Device buffers FP32; comparison in
// bf16 domain (2% of max). Numerics byte-identical to passing r3/r8/r10
// kernels (2-term f16 RNE splits, 3 MFMAs/product axis path; plain f16 arg
// path; pre-scaled x16, scores /256).
//
// Round-13: M=128 (32 pairs/block, grid 1024). Rationale: MfmaUtil pinned at
// ~25% across r10/r11/r12 regardless of occupancy/ILP; weight re-streaming
// from L2 (4.8GB aggregate at M=32, 16 MFMA per 6 weight loads) dominates
// block span. M=128 cuts weight traffic 4x and gives 64 MFMAs per 6 weight
// loads per kk (~310cyc MFMA self-hides L2 latency).
//  - 512 threads, 8 waves, nt=2 col-tiles/wave, acc1/accm = 128 AGPR
//    (launch_bounds(512,2) -> 256-reg budget, 1 block/CU; r11 proved
//    1 block/CU is not a loss).
//  - LDS 144KB static: bufH/bufL 64KB each (staging then h1 overlay) +
//    h1m 16KB. Sequential operand staging: stage axis -> pass0 ->
//    stage arg -> pass1.
//  - Weights double-buffered (1 kk ahead); A-frags read per-4-mt group.

typedef __attribute__((ext_vector_type(8))) _Float16 f16x8;
typedef __attribute__((ext_vector_type(8))) float f32x8;
typedef __attribute__((ext_vector_type(4))) float f32x4;

#define BH 32768            // B*HEADS pairs
#define OUT_ARG_OFF 8388608 // B*DIM

// ws layout in halfs (fragment-linear within each array)
#define O_WXA_H 0
#define O_WXA_L 65536
#define O_WXR_H 131072
#define O_WXR_L 196608
#define O_WRA_H 262144
#define O_WRR_H 327680
#define O_W2X_H 393216
#define O_W2X_L 458752
#define O_W2G_H 524288
#define WS_HALFS 589824     // 1179648 bytes

__device__ __forceinline__ void split16(float x, _Float16& hi, _Float16& lo) {
  float xs = x * 16.0f;
  _Float16 h = (_Float16)xs;      // RNE
  hi = h;
  lo = (_Float16)(xs - (float)h); // residual; product error ~2^-22
}

// fragment-linear index for weights: element (col o, k) -> tile (o>>4, k>>5),
// lane ((k>>3)&3)*16 + (o&15), slot j=k&7.
__device__ __forceinline__ int fragidx(int o, int k) {
  int ct = o >> 4, kk = k >> 5, lg = (k >> 3) & 3, l15 = o & 15, j = k & 7;
  return (ct * 8 + kk) * 512 + (lg * 16 + l15) * 8 + j;
}

// ---- prep: combined + split layer weights (x16-scaled, frag-linear) ----
__global__ void combine_weights(const float* __restrict__ Wx1, const float* __restrict__ Wr1,
                                const float* __restrict__ W2x, const float* __restrict__ W2g,
                                _Float16* __restrict__ ws) {
  int i = blockIdx.x * 256 + threadIdx.x;  // 0..65535 ; o=i>>8, k=i&255
  int o = i >> 8, k = i & 255;
  int d = fragidx(o, k);
  float a = Wx1[o * 512 + k], b = Wx1[o * 512 + 256 + k];
  _Float16 h, l;
  split16(a + b, h, l);          ws[O_WXA_H + d] = h; ws[O_WXA_L + d] = l;
  split16(0.5f * (b - a), h, l); ws[O_WXR_H + d] = h; ws[O_WXR_L + d] = l;
  a = Wr1[o * 512 + k]; b = Wr1[o * 512 + 256 + k];
  ws[O_WRA_H + d] = (_Float16)((a + b) * 16.0f);
  ws[O_WRR_H + d] = (_Float16)((0.5f * (b - a)) * 16.0f);
  split16(W2x[o * 256 + k], h, l); ws[O_W2X_H + d] = h; ws[O_W2X_L + d] = l;
  ws[O_W2G_H + d] = (_Float16)(W2g[o * 256 + k] * 16.0f);
}

#define MFMA16 __builtin_amdgcn_mfma_f32_16x16x32_f16

// stage one fp32 operand (128 rows x 256 cols) -> split16 -> swizzled LDS
__device__ __forceinline__ void stage128(const float* __restrict__ src, int g0, int tid,
                                         _Float16* bufH, _Float16* bufL) {
  #pragma unroll
  for (int c = 0; c < 8; ++c) {
    const int i   = c * 512 + tid;
    const int row = i >> 5;            // 0..127 ; n = row&3, pair = row>>2
    const int col = (i & 31) * 8;
    const int gofs = ((row & 3) * BH + g0 + (row >> 2)) * 256 + col;
    f32x8 v = *(const f32x8*)(src + gofs);
    f16x8 xh, xl;
    #pragma unroll
    for (int j = 0; j < 8; ++j) { _Float16 h, lo2; split16(v[j], h, lo2); xh[j] = h; xl[j] = lo2; }
    const int ad = row * 256 + (col ^ ((row & 7) << 3));
    *(f16x8*)(bufH + ad) = xh;
    *(f16x8*)(bufL + ad) = xl;
  }
}

// one GEMM1 operand pass (M=128): operand hi/lo in LDS; double-buffered weights.
__device__ __forceinline__ void gemm1_pass128(const _Float16* __restrict__ ws,
                                              int oBh, int oBl, int oBm,
                                              const _Float16* bufH, const _Float16* bufL,
                                              int ct0, int l, int l15, int lg,
                                              f32x4 (&acc1)[8][2], f32x4 (&accm)[8][2]) {
  f16x8 wh[2][2], wl[2][2], wm[2][2];
  #pragma unroll
  for (int nt = 0; nt < 2; ++nt) {
    const int fb = ((ct0 + nt) << 3) * 512 + l * 8;
    wh[0][nt] = *(const f16x8*)(ws + oBh + fb);
    wl[0][nt] = *(const f16x8*)(ws + oBl + fb);
    wm[0][nt] = *(const f16x8*)(ws + oBm + fb);
  }
  #pragma unroll
  for (int kk = 0; kk < 8; ++kk) {
    const int cur = kk & 1, nx = cur ^ 1;
    if (kk < 7) {
      #pragma unroll
      for (int nt = 0; nt < 2; ++nt) {
        const int fb = (((ct0 + nt) << 3) + kk + 1) * 512 + l * 8;
        wh[nx][nt] = *(const f16x8*)(ws + oBh + fb);
        wl[nx][nt] = *(const f16x8*)(ws + oBl + fb);
        wm[nx][nt] = *(const f16x8*)(ws + oBm + fb);
      }
    }
    #pragma unroll
    for (int grp = 0; grp < 2; ++grp) {
      f16x8 ah[4], al[4];
      #pragma unroll
      for (int q = 0; q < 4; ++q) {
        const int row = ((grp * 4 + q) << 4) + l15;
        const int ad  = row * 256 + (((kk << 5) + (lg << 3)) ^ ((row & 7) << 3));
        ah[q] = *(const f16x8*)(bufH + ad);
        al[q] = *(const f16x8*)(bufL + ad);
      }
      #pragma unroll
      for (int nt = 0; nt < 2; ++nt)
        #pragma unroll
        for (int q = 0; q < 4; ++q) {
          const int mt = grp * 4 + q;
          acc1[mt][nt] = MFMA16(ah[q], wh[cur][nt], acc1[mt][nt], 0, 0, 0);
          acc1[mt][nt] = MFMA16(al[q], wh[cur][nt], acc1[mt][nt], 0, 0, 0);
          acc1[mt][nt] = MFMA16(ah[q], wl[cur][nt], acc1[mt][nt], 0, 0, 0);
          accm[mt][nt] = MFMA16(ah[q], wm[cur][nt], accm[mt][nt], 0, 0, 0);
        }
    }
  }
}

__global__ __launch_bounds__(512, 2)
void cone_main(const float* __restrict__ axisF, const float* __restrict__ argF,
               const float* __restrict__ bx1, const float* __restrict__ br1,
               const float* __restrict__ bg2,
               const _Float16* __restrict__ ws, float* __restrict__ out)
{
  __shared__ __align__(16) _Float16 lds[73728];  // 144KB
  _Float16* bufH = lds;            // 128x256: axis hi -> arg hi -> h1h
  _Float16* bufL = lds + 32768;    // 128x256: axis lo -> arg lo -> h1l
  _Float16* h1m  = lds + 65536;    // 32x256: mean relu(h1_arg)

  const int tid = threadIdx.x;
  const int w   = tid >> 6;
  const int l   = tid & 63;
  const int l15 = l & 15;
  const int lg  = l >> 4;
  int bid = blockIdx.x;
  bid = ((bid & 7) << 7) + (bid >> 3);   // XCD swizzle (1024 % 8 == 0)
  const int g0 = bid << 5;               // 32 pairs/block
  const float s = 1.0f / 256.0f;
  const int ct0 = w << 1;                // this wave's first col-tile (+nt)

  f32x4 acc1[8][2], accm[8][2];
  #pragma unroll
  for (int mt = 0; mt < 8; ++mt)
    #pragma unroll
    for (int nt = 0; nt < 2; ++nt) { acc1[mt][nt] = (f32x4){0,0,0,0}; accm[mt][nt] = (f32x4){0,0,0,0}; }

  // ---- phase A: stage axis, axis-operand pass ----
  stage128(axisF, g0, tid, bufH, bufL);
  __syncthreads();
  gemm1_pass128(ws, O_WXA_H, O_WXA_L, O_WRA_H, bufH, bufL, ct0, l, l15, lg, acc1, accm);
  __syncthreads();

  // ---- phase B: stage arg into same buffers, arg-operand pass ----
  stage128(argF, g0, tid, bufH, bufL);
  __syncthreads();
  gemm1_pass128(ws, O_WXR_H, O_WXR_L, O_WRR_H, bufH, bufL, ct0, l, l15, lg, acc1, accm);
  __syncthreads();

  // ---- epilogue 1: h1 (split) overlays bufH/bufL; h1m mean ----
  #pragma unroll
  for (int nt = 0; nt < 2; ++nt) {
    const int c  = (w << 5) + (nt << 4) + l15;
    const float bvx = bx1[c];
    const float bvr = br1[c];
    #pragma unroll
    for (int mt = 0; mt < 8; ++mt) {
      #pragma unroll
      for (int r = 0; r < 4; ++r) {
        const int row = (mt << 4) + (lg << 2) + r;
        const float v = fmaxf(acc1[mt][nt][r] * s + bvx, 0.f);
        _Float16 h, lo2; split16(v, h, lo2);
        const int ad = row * 256 + (c ^ ((row & 7) << 3));
        bufH[ad] = h; bufL[ad] = lo2;
      }
      const int p = (mt << 2) + lg;   // pair index 0..31
      float sm = 0.f;
      #pragma unroll
      for (int r = 0; r < 4; ++r) sm += fmaxf(accm[mt][nt][r] * s + bvr, 0.f);
      h1m[p * 256 + (c ^ ((p & 7) << 3))] = (_Float16)(0.25f * sm * 16.0f);
    }
  }
  __syncthreads();

  // ---------- GEMM2 (attn logits, split) + gate (plain) ----------
  _Float16* h1h = bufH;
  _Float16* h1l = bufL;
  f32x4 acc2[8][2];
  f32x4 acc3[2][2];
  #pragma unroll
  for (int mt = 0; mt < 8; ++mt) { acc2[mt][0] = (f32x4){0,0,0,0}; acc2[mt][1] = (f32x4){0,0,0,0}; }
  acc3[0][0] = (f32x4){0,0,0,0}; acc3[0][1] = (f32x4){0,0,0,0};
  acc3[1][0] = (f32x4){0,0,0,0}; acc3[1][1] = (f32x4){0,0,0,0};
  {
    f16x8 wh[2][2], wl[2][2], wg[2][2];
    #pragma unroll
    for (int nt = 0; nt < 2; ++nt) {
      const int fb = ((ct0 + nt) << 3) * 512 + l * 8;
      wh[0][nt] = *(const f16x8*)(ws + O_W2X_H + fb);
      wl[0][nt] = *(const f16x8*)(ws + O_W2X_L + fb);
      wg[0][nt] = *(const f16x8*)(ws + O_W2G_H + fb);
    }
    #pragma unroll
    for (int kk = 0; kk < 8; ++kk) {
      const int cur = kk & 1, nx = cur ^ 1;
      if (kk < 7) {
        #pragma unroll
        for (int nt = 0; nt < 2; ++nt) {
          const int fb = (((ct0 + nt) << 3) + kk + 1) * 512 + l * 8;
          wh[nx][nt] = *(const f16x8*)(ws + O_W2X_H + fb);
          wl[nx][nt] = *(const f16x8*)(ws + O_W2X_L + fb);
          wg[nx][nt] = *(const f16x8*)(ws + O_W2G_H + fb);
        }
      }
      const int k0 = (kk << 5) + (lg << 3);
      #pragma unroll
      for (int grp = 0; grp < 2; ++grp) {
        f16x8 ah[4], al[4];
        #pragma unroll
        for (int q = 0; q < 4; ++q) {
          const int row = ((grp * 4 + q) << 4) + l15;
          const int ad  = row * 256 + (k0 ^ ((row & 7) << 3));
          ah[q] = *(const f16x8*)(h1h + ad);
          al[q] = *(const f16x8*)(h1l + ad);
        }
        #pragma unroll
        for (int nt = 0; nt < 2; ++nt)
          #pragma unroll
          for (int q = 0; q < 4; ++q) {
            const int mt = grp * 4 + q;
            acc2[mt][nt] = MFMA16(ah[q], wh[cur][nt], acc2[mt][nt], 0, 0, 0);
            acc2[mt][nt] = MFMA16(al[q], wh[cur][nt], acc2[mt][nt], 0, 0, 0);
            acc2[mt][nt] = MFMA16(ah[q], wl[cur][nt], acc2[mt][nt], 0, 0, 0);
          }
      }
      // gate: A = h1m rows (mt2*16 + l15)
      #pragma unroll
      for (int mt2 = 0; mt2 < 2; ++mt2) {
        const int row2 = (mt2 << 4) + l15;
        const f16x8 am = *(const f16x8*)(h1m + row2 * 256 + (k0 ^ ((row2 & 7) << 3)));
        #pragma unroll
        for (int nt = 0; nt < 2; ++nt)
          acc3[mt2][nt] = MFMA16(am, wg[cur][nt], acc3[mt2][nt], 0, 0, 0);
      }
    }
  }

  // ---- softmax over n (in-lane) + circular mean -> axis_out (fp32) ----
  // b_axis2 omitted: constant per column across n, cancels in softmax(axis=0).
  #pragma unroll
  for (int nt = 0; nt < 2; ++nt) {
    const int c = (w << 5) + (nt << 4) + l15;
    #pragma unroll
    for (int mt = 0; mt < 8; ++mt) {
      float lv[4];
      #pragma unroll
      for (int r = 0; r < 4; ++r) lv[r] = acc2[mt][nt][r] * s;
      const float mx = fmaxf(fmaxf(lv[0], lv[1]), fmaxf(lv[2], lv[3]));
      float e[4]; float sum = 0.f;
      #pragma unroll
      for (int r = 0; r < 4; ++r) { e[r] = __expf(lv[r] - mx); sum += e[r]; }
      const float inv = 1.f / sum;
      const int g = g0 + (mt << 2) + lg;
      float x = 0.f, y = 0.f;
      #pragma unroll
      for (int r = 0; r < 4; ++r) {
        const float av = axisF[(r * BH + g) * 256 + c];
        float sn, cs2;
        __sincosf(av, &sn, &cs2);
        const float at = e[r] * inv;
        x += at * cs2;
        y += at * sn;
      }
      if (fabsf(x) < 0.001f) x = 0.001f;
      out[g * 256 + c] = atan2f(y, x);
    }
  }

  // ---- sigmoid gate * min_n arg -> arg_out (fp32) ----
  #pragma unroll
  for (int nt = 0; nt < 2; ++nt) {
    const int c = (w << 5) + (nt << 4) + l15;
    const float bgv = bg2[c];
    #pragma unroll
    for (int mt2 = 0; mt2 < 2; ++mt2) {
      #pragma unroll
      for (int r = 0; r < 4; ++r) {
        const int p = (mt2 << 4) + (lg << 2) + r;   // pair index 0..31
        const int g = g0 + p;
        const float gate = 1.f / (1.f + __expf(-(acc3[mt2][nt][r] * s + bgv)));
        float mn = argF[g * 256 + c];
        #pragma unroll
        for (int n = 1; n < 4; ++n)
          mn = fminf(mn, argF[(n * BH + g) * 256 + c]);
        out[OUT_ARG_OFF + g * 256 + c] = mn * gate;
      }
    }
  }
}

extern "C" void kernel_launch(void* const* d_in, const int* in_sizes, int n_in,
                              void* d_out, int out_size, void* d_ws, size_t ws_size,
                              hipStream_t stream) {
  const float* axisF = (const float*)d_in[0];
  const float* argF  = (const float*)d_in[1];
  const float* Wx1   = (const float*)d_in[2];
  const float* bx1   = (const float*)d_in[3];
  const float* Wr1   = (const float*)d_in[4];
  const float* br1   = (const float*)d_in[5];
  const float* W2x   = (const float*)d_in[6];
  // d_in[7] = b_axis2: constant over n at fixed column -> cancels in softmax
  const float* W2g   = (const float*)d_in[8];
  const float* bg2   = (const float*)d_in[9];
  float* out = (float*)d_out;
  _Float16* ws = (_Float16*)d_ws;

  combine_weights<<<256, 256, 0, stream>>>(Wx1, Wr1, W2x, W2g, ws);
  cone_main<<<1024, 512, 0, stream>>>(axisF, argF, bx1, br1, bg2, ws, out);
}